// Round 7
// baseline (353.256 us; speedup 1.0000x reference)
//
#include <hip/hip_runtime.h>
#include <math.h>

#define T 2048
#define HID 2048
#define NH 32
#define NKV 4
#define HD 128
#define QKV_DIM 5120   // (NH + 2*NKV) * HD
#define OD 4096        // NH * HD
// SCALE * log2(e): scores go straight to log2 domain
#define C2LOG 0.12751743f
#define MFIX 6.0f      // fixed softmax exponent shift (cancels in O/l)

typedef _Float16 half8 __attribute__((ext_vector_type(8)));
typedef _Float16 half4v __attribute__((ext_vector_type(4)));
typedef float floatx4 __attribute__((ext_vector_type(4)));

// async global->LDS, 16B per lane; LDS dest is wave-uniform base + lane*16
#define GLD16(gp, lp) __builtin_amdgcn_global_load_lds( \
    (const __attribute__((address_space(1))) void*)(gp), \
    (__attribute__((address_space(3))) void*)(lp), 16, 0, 0)

// ---------------- fused fp32 -> fp16 conversion (hidden, w_qkv, w_o) -------
__global__ __launch_bounds__(256)
void cvt_all(const float* __restrict__ h, const float* __restrict__ wq,
             const float* __restrict__ wo, _Float16* __restrict__ out) {
    size_t i = ((size_t)blockIdx.x * 256 + threadIdx.x) * 4;
    const float* src;
    size_t off;
    if (i < (size_t)T * HID)                        { src = h;  off = i; }
    else if (i < (size_t)T * HID + (size_t)QKV_DIM * HID)
                                                    { src = wq; off = i - (size_t)T * HID; }
    else                                            { src = wo; off = i - (size_t)T * HID - (size_t)QKV_DIM * HID; }
    float4 v = *(const float4*)(src + off);
    half4v o = { (_Float16)v.x, (_Float16)v.y, (_Float16)v.z, (_Float16)v.w };
    *(half4v*)(out + i) = o;
}

// -------- split-K GEMM (NT), fp16 partial out, BK=64 (2x 32-col panels) ----
__global__ __launch_bounds__(256)
void gemm_sk_h(const _Float16* __restrict__ A, const _Float16* __restrict__ B,
               _Float16* __restrict__ p0, _Float16* __restrict__ p1,
               int M, int N, int K, int KS) {
    __shared__ __align__(16) _Float16 Asm[8192];  // [2 panels][128][32]
    __shared__ __align__(16) _Float16 Bsm[8192];
    int tid = threadIdx.x;
    int wave = tid >> 6, lane = tid & 63;
    int quad = lane >> 4, l16 = lane & 15;
    int m0 = blockIdx.y * 128, n0 = blockIdx.x * 128;
    int koff = blockIdx.z * KS;
    _Float16* C = blockIdx.z ? p1 : p0;
    int wm = (wave >> 1) * 64, wn = (wave & 1) * 64;
    const _Float16* Ag = A + (size_t)(m0 + (tid >> 2)) * K + koff + (tid & 3) * 8;
    const _Float16* Bg = B + (size_t)(n0 + (tid >> 2)) * K + koff + (tid & 3) * 8;
    size_t row64 = (size_t)64 * K;
    _Float16* AsmW = Asm + wave * 512;
    _Float16* BsmW = Bsm + wave * 512;
    floatx4 acc[4][4] = {};
    for (int k0 = 0; k0 < KS; k0 += 64) {
        __syncthreads();
        GLD16(Ag, AsmW);
        GLD16(Ag + row64, AsmW + 2048);
        GLD16(Ag + 32, AsmW + 4096);
        GLD16(Ag + row64 + 32, AsmW + 6144);
        GLD16(Bg, BsmW);
        GLD16(Bg + row64, BsmW + 2048);
        GLD16(Bg + 32, BsmW + 4096);
        GLD16(Bg + row64 + 32, BsmW + 6144);
        Ag += 64; Bg += 64;
        __syncthreads();
        #pragma unroll
        for (int p = 0; p < 2; p++) {
            half8 af[4], bf[4];
            #pragma unroll
            for (int i = 0; i < 4; i++)
                af[i] = *(const half8*)&Asm[p * 4096 + (wm + i * 16 + l16) * 32 + quad * 8];
            #pragma unroll
            for (int j = 0; j < 4; j++)
                bf[j] = *(const half8*)&Bsm[p * 4096 + (wn + j * 16 + l16) * 32 + quad * 8];
            #pragma unroll
            for (int i = 0; i < 4; i++)
                #pragma unroll
                for (int j = 0; j < 4; j++)
                    acc[i][j] = __builtin_amdgcn_mfma_f32_16x16x32_f16(af[i], bf[j], acc[i][j], 0, 0, 0);
        }
    }
    #pragma unroll
    for (int i = 0; i < 4; i++) {
        int row = m0 + wm + i * 16 + quad * 4;
        #pragma unroll
        for (int j = 0; j < 4; j++) {
            int col = n0 + wn + j * 16 + l16;
            #pragma unroll
            for (int r = 0; r < 4; r++)
                C[(size_t)(row + r) * N + col] = (_Float16)acc[i][j][r];
        }
    }
}

// -------- split-K GEMM (NT), fp16 partials x4, BK=64 -----------------------
__global__ __launch_bounds__(256)
void gemm_sk_f(const _Float16* __restrict__ A, const _Float16* __restrict__ B,
               _Float16* __restrict__ p0, _Float16* __restrict__ p1,
               _Float16* __restrict__ p2, _Float16* __restrict__ p3,
               int M, int N, int K, int KS) {
    __shared__ __align__(16) _Float16 Asm[8192];
    __shared__ __align__(16) _Float16 Bsm[8192];
    int tid = threadIdx.x;
    int wave = tid >> 6, lane = tid & 63;
    int quad = lane >> 4, l16 = lane & 15;
    int m0 = blockIdx.y * 128, n0 = blockIdx.x * 128;
    int bz = blockIdx.z;
    int koff = bz * KS;
    _Float16* C = (bz == 0) ? p0 : (bz == 1) ? p1 : (bz == 2) ? p2 : p3;
    int wm = (wave >> 1) * 64, wn = (wave & 1) * 64;
    const _Float16* Ag = A + (size_t)(m0 + (tid >> 2)) * K + koff + (tid & 3) * 8;
    const _Float16* Bg = B + (size_t)(n0 + (tid >> 2)) * K + koff + (tid & 3) * 8;
    size_t row64 = (size_t)64 * K;
    _Float16* AsmW = Asm + wave * 512;
    _Float16* BsmW = Bsm + wave * 512;
    floatx4 acc[4][4] = {};
    for (int k0 = 0; k0 < KS; k0 += 64) {
        __syncthreads();
        GLD16(Ag, AsmW);
        GLD16(Ag + row64, AsmW + 2048);
        GLD16(Ag + 32, AsmW + 4096);
        GLD16(Ag + row64 + 32, AsmW + 6144);
        GLD16(Bg, BsmW);
        GLD16(Bg + row64, BsmW + 2048);
        GLD16(Bg + 32, BsmW + 4096);
        GLD16(Bg + row64 + 32, BsmW + 6144);
        Ag += 64; Bg += 64;
        __syncthreads();
        #pragma unroll
        for (int p = 0; p < 2; p++) {
            half8 af[4], bf[4];
            #pragma unroll
            for (int i = 0; i < 4; i++)
                af[i] = *(const half8*)&Asm[p * 4096 + (wm + i * 16 + l16) * 32 + quad * 8];
            #pragma unroll
            for (int j = 0; j < 4; j++)
                bf[j] = *(const half8*)&Bsm[p * 4096 + (wn + j * 16 + l16) * 32 + quad * 8];
            #pragma unroll
            for (int i = 0; i < 4; i++)
                #pragma unroll
                for (int j = 0; j < 4; j++)
                    acc[i][j] = __builtin_amdgcn_mfma_f32_16x16x32_f16(af[i], bf[j], acc[i][j], 0, 0, 0);
        }
    }
    #pragma unroll
    for (int i = 0; i < 4; i++) {
        int row = m0 + wm + i * 16 + quad * 4;
        #pragma unroll
        for (int j = 0; j < 4; j++) {
            int col = n0 + wn + j * 16 + l16;
            #pragma unroll
            for (int r = 0; r < 4; r++)
                C[(size_t)(row + r) * N + col] = (_Float16)acc[i][j][r];
        }
    }
}

// ---------------- reduce 4 fp16 partials -> fp32 out ------------------------
__global__ __launch_bounds__(256)
void reduce4(const _Float16* __restrict__ p0, const _Float16* __restrict__ p1,
             const _Float16* __restrict__ p2, const _Float16* __restrict__ p3,
             float* __restrict__ out) {
    size_t i = ((size_t)blockIdx.x * 256 + threadIdx.x) * 4;
    half4v a = *(const half4v*)(p0 + i);
    half4v b = *(const half4v*)(p1 + i);
    half4v c = *(const half4v*)(p2 + i);
    half4v d = *(const half4v*)(p3 + i);
    float4 o = { (float)a.x + (float)b.x + (float)c.x + (float)d.x,
                 (float)a.y + (float)b.y + (float)c.y + (float)d.y,
                 (float)a.z + (float)b.z + (float)c.z + (float)d.z,
                 (float)a.w + (float)b.w + (float)c.w + (float)d.w };
    *(float4*)(out + i) = o;
}

// ---------------- RMSNorm + RoPE + reorder (sums 2 fp16 partials) ----------
__global__ __launch_bounds__(256)
void qkv_post(const _Float16* __restrict__ qp0, const _Float16* __restrict__ qp1,
              const int* __restrict__ positions,
              const float* __restrict__ qw, const float* __restrict__ kw,
              _Float16* __restrict__ Qb, _Float16* __restrict__ Kb,
              _Float16* __restrict__ Vt) {
    int t = blockIdx.x;
    int wave = threadIdx.x >> 6, lane = threadIdx.x & 63;
    float pos = (float)positions[t];
    float f = exp2f(-(float)lane * (19.9315685693241741f / 64.0f));
    float ang = pos * f;
    float s = sinf(ang), c = cosf(ang);
    const _Float16* r0 = qp0 + (size_t)t * QKV_DIM;
    const _Float16* r1 = qp1 + (size_t)t * QKV_DIM;
    for (int hh = wave; hh < NH + 2 * NKV; hh += 4) {
        float x1 = (float)r0[hh * HD + lane] + (float)r1[hh * HD + lane];
        float x2 = (float)r0[hh * HD + lane + 64] + (float)r1[hh * HD + lane + 64];
        if (hh < NH + NKV) {
            float ss = x1 * x1 + x2 * x2;
            for (int o = 1; o < 64; o <<= 1) ss += __shfl_xor(ss, o);
            float inv = rsqrtf(ss * (1.0f / HD) + 1e-6f);
            const float* w = (hh < NH) ? qw : kw;
            x1 = x1 * inv * w[lane];
            x2 = x2 * inv * w[lane + 64];
            float y1 = x1 * c - x2 * s;
            float y2 = x2 * c + x1 * s;
            _Float16* dst;
            if (hh < NH) dst = Qb + ((size_t)hh * T + t) * HD;
            else         dst = Kb + ((size_t)(hh - NH) * T + t) * HD;
            dst[lane]      = (_Float16)y1;
            dst[lane + 64] = (_Float16)y2;
        } else {
            int hk = hh - NH - NKV;
            Vt[((size_t)hk * HD + lane) * T + t]      = (_Float16)x1;
            Vt[((size_t)hk * HD + lane + 64) * T + t] = (_Float16)x2;
        }
    }
}

// ---------------- Flash attention: 1024 blocks x 2 waves, G=2 --------------
// Each wave owns 32 q-rows (2 groups of 16): every K/V fragment read from LDS
// feeds 2 MFMAs -> LDS bytes/MFMA halved vs G=1. LDS 36 KB -> 4 blocks/CU
// (8 wave-streams/CU from 4 independent blocks). r4 balanced schedule.
// PV computed as O^T = Vt-frag (A) x P-frag (B): b64 epilogue stores.
__global__ __launch_bounds__(128)
void attn(const _Float16* __restrict__ Qb, const _Float16* __restrict__ Kb,
          const _Float16* __restrict__ Vt, _Float16* __restrict__ Ob) {
    __shared__ __align__(16) _Float16 Ksm[8192];    // [64][128] col-block ^ (row&7)
    __shared__ __align__(16) _Float16 Vsm[8192];    // [128][64] col-block ^ (row&7)
    __shared__ __align__(16) _Float16 Psm[2][1024]; // per-wave [16][64] swizzled
    int b = blockIdx.x;
    int h = b & 31;
    int quarter = b >> 8;
    int iq = (b & 255) >> 5;
    int qt = (quarter == 0) ? 31 - iq : (quarter == 1) ? iq
           : (quarter == 2) ? 23 - iq : 8 + iq;
    int hk = h >> 3;
    int tid = threadIdx.x, wave = tid >> 6, lane = tid & 63;
    int quad = lane >> 4, l16 = lane & 15;
    int q0 = qt * 64;
    int wbase = q0 + wave * 32;

    half8 aq[2][4];
    #pragma unroll
    for (int g = 0; g < 2; g++) {
        const _Float16* qp = Qb + ((size_t)h * T + wbase + g * 16 + l16) * HD + quad * 8;
        #pragma unroll
        for (int dk = 0; dk < 4; dk++)
            aq[g][dk] = *(const half8*)(qp + dk * 32);
    }
    floatx4 o_acc[2][8] = {};
    float lpart[2][4] = {};

    int krow = wave * 4 + (lane >> 4);       // 0..7
    const _Float16* Kg = Kb + ((size_t)hk * T + krow) * HD + ((lane & 15) ^ (krow & 7)) * 8;
    int vrow = wave * 8 + (lane >> 3);       // 0..15
    const _Float16* Vg = Vt + ((size_t)hk * HD + vrow) * T + ((lane & 7) ^ (vrow & 7)) * 8;
    _Float16* KsmW = Ksm + wave * 512;
    _Float16* VsmW = Vsm + wave * 512;
    _Float16* PsmW = Psm[wave];

    int ntiles = qt + 1;
    for (int it = 0; it < ntiles; it++) {
        int kv0 = it * 64;
        __syncthreads();
        {
            const _Float16* kg = Kg + (size_t)kv0 * HD;
            const _Float16* vg = Vg + kv0;
            #pragma unroll
            for (int c = 0; c < 8; c++) {
                GLD16(kg + (size_t)c * (8 * HD), KsmW + c * 1024);
                GLD16(vg + (size_t)c * (16 * T), VsmW + c * 1024);
            }
        }
        __syncthreads();

        bool act[2];
        act[0] = (kv0 <= wbase + 15);
        act[1] = (kv0 <= wbase + 31);

        // S = Q K^T (K frags shared across both row-groups)
        floatx4 sfr[2][4];
        #pragma unroll
        for (int sn = 0; sn < 4; sn++) {
            int row = sn * 16 + l16;
            int rs = row & 7;
            half8 kf[4];
            #pragma unroll
            for (int dk = 0; dk < 4; dk++)
                kf[dk] = *(const half8*)&Ksm[row * 128 + ((dk * 4 + quad) ^ rs) * 8];
            #pragma unroll
            for (int g = 0; g < 2; g++) {
                if (!act[g]) continue;
                floatx4 a = {};
                #pragma unroll
                for (int dk = 0; dk < 4; dk++)
                    a = __builtin_amdgcn_mfma_f32_16x16x32_f16(aq[g][dk], kf[dk], a, 0, 0, 0);
                sfr[g][sn] = a;
            }
        }

        half8 ap[2][2];
        #pragma unroll
        for (int g = 0; g < 2; g++) {
            if (!act[g]) continue;
            int bg = wbase + g * 16;
            bool needmask = (kv0 + 63 > bg);
            int rq = bg + quad * 4;
            #pragma unroll
            for (int sn = 0; sn < 4; sn++) {
                int kv = kv0 + sn * 16 + l16;
                #pragma unroll
                for (int r = 0; r < 4; r++) {
                    float p = __builtin_amdgcn_exp2f(
                        __builtin_fmaf(sfr[g][sn][r], C2LOG, -MFIX));
                    if (needmask) p = (kv <= rq + r) ? p : 0.0f;
                    lpart[g][r] += p;
                    int prow = quad * 4 + r;
                    int cb = sn * 2 + (l16 >> 3);
                    PsmW[prow * 64 + ((cb ^ (prow & 7)) * 8 + (l16 & 7))] = (_Float16)p;
                }
            }
            // same-wave DS ops are in-order; no barrier needed
            ap[g][0] = *(const half8*)&PsmW[l16 * 64 + ((quad ^ (l16 & 7)) * 8)];
            ap[g][1] = *(const half8*)&PsmW[l16 * 64 + (((4 + quad) ^ (l16 & 7)) * 8)];
        }

        // O^T += Vt-frag * P-frag (V frags shared across both row-groups)
        #pragma unroll
        for (int dn = 0; dn < 8; dn++) {
            int row = dn * 16 + l16;
            int rs = row & 7;
            half8 v0 = *(const half8*)&Vsm[row * 64 + ((quad ^ rs) * 8)];
            half8 v1 = *(const half8*)&Vsm[row * 64 + (((4 + quad) ^ rs) * 8)];
            #pragma unroll
            for (int g = 0; g < 2; g++) {
                if (!act[g]) continue;
                o_acc[g][dn] = __builtin_amdgcn_mfma_f32_16x16x32_f16(v0, ap[g][0], o_acc[g][dn], 0, 0, 0);
                o_acc[g][dn] = __builtin_amdgcn_mfma_f32_16x16x32_f16(v1, ap[g][1], o_acc[g][dn], 0, 0, 0);
            }
        }
    }

    // l reduction over 16 column-lanes, exchange via LDS to get 1/l per q-lane
    #pragma unroll
    for (int g = 0; g < 2; g++)
        #pragma unroll
        for (int o = 1; o < 16; o <<= 1)
            #pragma unroll
            for (int r = 0; r < 4; r++)
                lpart[g][r] += __shfl_xor(lpart[g][r], o);
    float* Lsm = (float*)PsmW;
    if (l16 == 0) {
        #pragma unroll
        for (int g = 0; g < 2; g++)
            #pragma unroll
            for (int r = 0; r < 4; r++)
                Lsm[g * 16 + quad * 4 + r] = lpart[g][r];
    }
    #pragma unroll
    for (int g = 0; g < 2; g++) {
        float linv = 1.0f / Lsm[g * 16 + l16];
        int trow = wbase + g * 16 + l16;
        #pragma unroll
        for (int dn = 0; dn < 8; dn++) {
            half4v st = { (_Float16)(o_acc[g][dn][0] * linv),
                          (_Float16)(o_acc[g][dn][1] * linv),
                          (_Float16)(o_acc[g][dn][2] * linv),
                          (_Float16)(o_acc[g][dn][3] * linv) };
            *(half4v*)(Ob + (size_t)trow * OD + h * HD + dn * 16 + quad * 4) = st;
        }
    }
}

extern "C" void kernel_launch(void* const* d_in, const int* in_sizes, int n_in,
                              void* d_out, int out_size, void* d_ws, size_t ws_size,
                              hipStream_t stream) {
    const int*   positions = (const int*)d_in[0];
    const float* hidden    = (const float*)d_in[1];
    const float* w_qkv     = (const float*)d_in[2];
    const float* w_o       = (const float*)d_in[3];
    const float* q_norm_w  = (const float*)d_in[4];
    const float* k_norm_w  = (const float*)d_in[5];
    float* out = (float*)d_out;

    const size_t MiB = 1048576;
    char* ws = (char*)d_ws;
    _Float16* hb    = (_Float16*)(ws);
    _Float16* wqkvb = (_Float16*)(ws + 8 * MiB);
    _Float16* wob   = (_Float16*)(ws + 28 * MiB);
    _Float16* qkvp0 = (_Float16*)(ws + 44 * MiB);
    _Float16* qkvp1 = (_Float16*)(ws + 64 * MiB);
    _Float16* Qb    = (_Float16*)(ws + 84 * MiB);
    _Float16* Kb    = (_Float16*)(ws + 100 * MiB);
    _Float16* Vt    = (_Float16*)(ws + 102 * MiB);
    _Float16* Ob    = (_Float16*)(ws + 104 * MiB);
    _Float16* op0   = (_Float16*)(ws);
    _Float16* op1   = (_Float16*)(ws + 9 * MiB);
    _Float16* op2   = (_Float16*)(ws + 44 * MiB);
    _Float16* op3   = (_Float16*)(ws + 53 * MiB);

    cvt_all<<<22528, 256, 0, stream>>>(hidden, w_qkv, w_o, hb);

    // qkv partial GEMMs: split-K=2 over K=2048
    gemm_sk_h<<<dim3(QKV_DIM / 128, T / 128, 2), 256, 0, stream>>>(
        hb, wqkvb, qkvp0, qkvp1, T, QKV_DIM, HID, HID / 2);

    qkv_post<<<T, 256, 0, stream>>>(qkvp0, qkvp1, positions, q_norm_w, k_norm_w, Qb, Kb, Vt);

    attn<<<1024, 128, 0, stream>>>(Qb, Kb, Vt, Ob);

    // out projection: split-K=4 over K=4096
    gemm_sk_f<<<dim3(HID / 128, T / 128, 4), 256, 0, stream>>>(
        Ob, wob, op0, op1, op2, op3, T, HID, OD, OD / 4);
    reduce4<<<T * HID / 1024, 256, 0, stream>>>(op0, op1, op2, op3, out);
}